// Round 2
// baseline (657.235 us; speedup 1.0000x reference)
//
#include <hip/hip_runtime.h>

// ---------------------------------------------------------------------------
// GCN 2-layer forward, MI355X.
// Pipeline per call:
//   1. cnt[dst]++ (in-degree)            -> dinv = rsqrt(cnt+1)
//   2. exclusive scan(cnt) -> row_ptr    (3-kernel scan)
//   3. fill CSR (src list sorted by dst) via atomic cursors
//   4. h  = x @ W1            (f32 tiled GEMM, vector ALU)
//   5. out1 = relu(agg(h)+b1) (gather per node, no atomics)  -> d_out (temp)
//   6. h2 = out1 @ W2
//   7. d_out = relu(agg(h2)+b2)
// ---------------------------------------------------------------------------

#define NN 100000

__global__ __launch_bounds__(256) void k_count(const int* __restrict__ dst,
                                               int* __restrict__ cnt, int E) {
  int e = blockIdx.x * 256 + threadIdx.x;
  if (e < E) atomicAdd(&cnt[dst[e]], 1);
}

__global__ __launch_bounds__(256) void k_dinv(const int* __restrict__ cnt,
                                              float* __restrict__ dinv, int N) {
  int i = blockIdx.x * 256 + threadIdx.x;
  if (i < N) dinv[i] = rsqrtf((float)cnt[i] + 1.0f);
}

__global__ __launch_bounds__(256) void k_blocksum(const int* __restrict__ cnt,
                                                  int* __restrict__ bsum, int N) {
  __shared__ int s[256];
  int i = blockIdx.x * 256 + threadIdx.x;
  s[threadIdx.x] = (i < N) ? cnt[i] : 0;
  __syncthreads();
  for (int off = 128; off > 0; off >>= 1) {
    if (threadIdx.x < off) s[threadIdx.x] += s[threadIdx.x + off];
    __syncthreads();
  }
  if (threadIdx.x == 0) bsum[blockIdx.x] = s[0];
}

// single block, NB <= 512: exclusive-scan the block sums in place
__global__ __launch_bounds__(512) void k_scan_bsum(int* __restrict__ bsum, int NB,
                                                   int* __restrict__ row_ptr,
                                                   int N, int E) {
  __shared__ int s[512];
  int t = threadIdx.x;
  int v = (t < NB) ? bsum[t] : 0;
  s[t] = v;
  __syncthreads();
  for (int off = 1; off < 512; off <<= 1) {
    int x = (t >= off) ? s[t - off] : 0;
    __syncthreads();
    s[t] += x;
    __syncthreads();
  }
  if (t < NB) bsum[t] = s[t] - v;  // exclusive
  if (t == 0) row_ptr[N] = E;
}

__global__ __launch_bounds__(256) void k_scatter_scan(const int* __restrict__ cnt,
                                                      const int* __restrict__ bsum,
                                                      int* __restrict__ row_ptr, int N) {
  __shared__ int s[256];
  int t = threadIdx.x;
  int i = blockIdx.x * 256 + t;
  int v = (i < N) ? cnt[i] : 0;
  s[t] = v;
  __syncthreads();
  for (int off = 1; off < 256; off <<= 1) {
    int x = (t >= off) ? s[t - off] : 0;
    __syncthreads();
    s[t] += x;
    __syncthreads();
  }
  if (i < N) row_ptr[i] = bsum[blockIdx.x] + s[t] - v;  // global exclusive prefix
}

__global__ __launch_bounds__(256) void k_fill(const int* __restrict__ src,
                                              const int* __restrict__ dst,
                                              int* __restrict__ cursor,
                                              int* __restrict__ csr_src, int E) {
  int e = blockIdx.x * 256 + threadIdx.x;
  if (e < E) {
    int d = dst[e];
    int pos = atomicAdd(&cursor[d], 1);
    csr_src[pos] = src[e];
  }
}

// ---------------------------------------------------------------------------
// C[M][128] = X[M][128] @ W[128][128], f32. Block tile 64 rows x 128 cols,
// per-thread 4 rows x 8 cols. X tile staged transposed in LDS, W chunk staged.
// ---------------------------------------------------------------------------
#define KC 32
__global__ __launch_bounds__(256) void k_gemm128(const float* __restrict__ X,
                                                 const float* __restrict__ W,
                                                 float* __restrict__ C, int M) {
  __shared__ float xs[KC][68];   // xs[k][row], row-stride 68 floats
  __shared__ float wt[KC][132];  // wt[k][col]

  const int t = threadIdx.x;
  const int row0 = blockIdx.x * 64;
  const int trow = t >> 4;  // 0..15 -> 4 rows each
  const int tcol = t & 15;  // 0..15 -> 8 cols each

  float acc[4][8];
#pragma unroll
  for (int i = 0; i < 4; i++)
#pragma unroll
    for (int j = 0; j < 8; j++) acc[i][j] = 0.f;

  for (int k0 = 0; k0 < 128; k0 += KC) {
    // stage X tile (64 rows x KC), transposed: 8 floats per thread
    {
      int r = t >> 2;            // 0..63
      int kk = (t & 3) * 8;      // 0,8,16,24
      int grow = row0 + r;
      float4 v0, v1;
      if (grow < M) {
        const float* p = X + (size_t)grow * 128 + k0 + kk;
        v0 = *(const float4*)p;
        v1 = *(const float4*)(p + 4);
      } else {
        v0 = make_float4(0.f, 0.f, 0.f, 0.f);
        v1 = v0;
      }
      xs[kk + 0][r] = v0.x; xs[kk + 1][r] = v0.y;
      xs[kk + 2][r] = v0.z; xs[kk + 3][r] = v0.w;
      xs[kk + 4][r] = v1.x; xs[kk + 5][r] = v1.y;
      xs[kk + 6][r] = v1.z; xs[kk + 7][r] = v1.w;
    }
    // stage W chunk (KC x 128): 4 float4 per thread
    {
#pragma unroll
      for (int q = 0; q < 4; q++) {
        int f4 = t + q * 256;  // 0..1023
        int k = f4 >> 5;
        int c4 = f4 & 31;
        float4 v = *(const float4*)(W + (size_t)(k0 + k) * 128 + c4 * 4);
        *(float4*)&wt[k][c4 * 4] = v;
      }
    }
    __syncthreads();

#pragma unroll
    for (int k = 0; k < KC; k++) {
      float4 a = *(const float4*)&xs[k][trow * 4];
      float4 w0 = *(const float4*)&wt[k][tcol * 8];
      float4 w1 = *(const float4*)&wt[k][tcol * 8 + 4];
      float av[4] = {a.x, a.y, a.z, a.w};
      float wv[8] = {w0.x, w0.y, w0.z, w0.w, w1.x, w1.y, w1.z, w1.w};
#pragma unroll
      for (int i = 0; i < 4; i++)
#pragma unroll
        for (int j = 0; j < 8; j++) acc[i][j] = fmaf(av[i], wv[j], acc[i][j]);
    }
    __syncthreads();
  }

#pragma unroll
  for (int i = 0; i < 4; i++) {
    int r = row0 + trow * 4 + i;
    if (r < M) {
      float* p = C + (size_t)r * 128 + tcol * 8;
      *(float4*)p = make_float4(acc[i][0], acc[i][1], acc[i][2], acc[i][3]);
      *(float4*)(p + 4) = make_float4(acc[i][4], acc[i][5], acc[i][6], acc[i][7]);
    }
  }
}

// ---------------------------------------------------------------------------
// One block (128 threads) per node: gather-accumulate in-edges, add self-loop
// + bias, relu, write. No atomics. 2-deep unroll for memory-level parallelism.
// out[n][t] = relu( (sum_e h[src_e][t]*dinv[src_e])*dinv[n] + h[n][t]*dinv[n]^2 + b[t] )
// ---------------------------------------------------------------------------
__global__ __launch_bounds__(128) void k_agg(const int* __restrict__ row_ptr,
                                             const int* __restrict__ csr_src,
                                             const float* __restrict__ dinv,
                                             const float* __restrict__ h,
                                             const float* __restrict__ bias,
                                             float* __restrict__ out) {
  const int node = blockIdx.x;
  const int t = threadIdx.x;
  const int e0 = row_ptr[node];
  const int e1 = row_ptr[node + 1];

  float acc = 0.f;
  int e = e0;
  for (; e + 2 <= e1; e += 2) {
    int s0 = csr_src[e];
    int s1 = csr_src[e + 1];
    float d0 = dinv[s0];
    float d1 = dinv[s1];
    float h0 = h[(size_t)s0 * 128 + t];
    float h1 = h[(size_t)s1 * 128 + t];
    acc = fmaf(h0, d0, acc);
    acc = fmaf(h1, d1, acc);
  }
  if (e < e1) {
    int s0 = csr_src[e];
    acc = fmaf(h[(size_t)s0 * 128 + t], dinv[s0], acc);
  }
  float dv = dinv[node];
  float self = h[(size_t)node * 128 + t];
  float v = fmaf(acc, dv, self * dv * dv) + bias[t];
  out[(size_t)node * 128 + t] = fmaxf(v, 0.f);
}

// ---------------------------------------------------------------------------

extern "C" void kernel_launch(void* const* d_in, const int* in_sizes, int n_in,
                              void* d_out, int out_size, void* d_ws, size_t ws_size,
                              hipStream_t stream) {
  const float* x  = (const float*)d_in[0];
  const int*   ei = (const int*)d_in[1];
  const float* W1 = (const float*)d_in[2];
  const float* b1 = (const float*)d_in[3];
  const float* W2 = (const float*)d_in[4];
  const float* b2 = (const float*)d_in[5];
  float* out = (float*)d_out;

  const int N = NN;
  const int E = in_sizes[1] / 2;
  const int* src = ei;
  const int* dst = ei + E;

  // workspace carve-up (256B aligned)
  char* w = (char*)d_ws;
  auto alloc = [&](size_t bytes) {
    char* p = w;
    w += (bytes + 255) & ~(size_t)255;
    return p;
  };
  float* dinv    = (float*)alloc((size_t)N * 4);
  int*   cnt     = (int*)alloc((size_t)N * 4);
  int*   row_ptr = (int*)alloc((size_t)(N + 1) * 4);
  int*   cursor  = (int*)alloc((size_t)N * 4);
  int*   bsum    = (int*)alloc(512 * 4);
  int*   csr_src = (int*)alloc((size_t)E * 4);
  float* h       = (float*)alloc((size_t)N * 128 * 4);

  const int NB = (N + 255) / 256;  // 391

  hipMemsetAsync(cnt, 0, (size_t)N * 4, stream);
  k_count<<<(E + 255) / 256, 256, 0, stream>>>(dst, cnt, E);
  k_dinv<<<NB, 256, 0, stream>>>(cnt, dinv, N);
  k_blocksum<<<NB, 256, 0, stream>>>(cnt, bsum, N);
  k_scan_bsum<<<1, 512, 0, stream>>>(bsum, NB, row_ptr, N, E);
  k_scatter_scan<<<NB, 256, 0, stream>>>(cnt, bsum, row_ptr, N);
  hipMemcpyAsync(cursor, row_ptr, (size_t)N * 4, hipMemcpyDeviceToDevice, stream);
  k_fill<<<(E + 255) / 256, 256, 0, stream>>>(src, dst, cursor, csr_src, E);

  // layer 1
  k_gemm128<<<(N + 63) / 64, 256, 0, stream>>>(x, W1, h, N);
  k_agg<<<N, 128, 0, stream>>>(row_ptr, csr_src, dinv, h, b1, out);  // out1 -> d_out (temp)
  // layer 2
  k_gemm128<<<(N + 63) / 64, 256, 0, stream>>>(out, W2, h, N);
  k_agg<<<N, 128, 0, stream>>>(row_ptr, csr_src, dinv, h, b2, out);
}

// Round 3
// 537.911 us; speedup vs baseline: 1.2218x; 1.2218x over previous
//
#include <hip/hip_runtime.h>

// ---------------------------------------------------------------------------
// GCN 2-layer forward, MI355X.
//   CSR build (count -> scan -> fill), then per layer:
//     GEMM (f32 vector-ALU) with epilogue hs = bf16(h * dinv[row])
//     agg: out[n] = relu( dinv[n] * (sum_e hs[src_e] + hs[n]) + b )
//   Gather reads bf16 rows (256B) -- halves the dominant HBM/L2-fill traffic
//   vs f32, and the dinv[src] random load is folded into the GEMM epilogue.
// ---------------------------------------------------------------------------

#define NN 100000

__device__ __forceinline__ ushort f2bf(float f) {
  unsigned u = __float_as_uint(f);
  unsigned r = (u + 0x7fffu + ((u >> 16) & 1u)) >> 16;  // round-to-nearest-even
  return (ushort)r;
}
__device__ __forceinline__ float bf2f(ushort s) {
  return __uint_as_float(((unsigned)s) << 16);
}

__global__ __launch_bounds__(256) void k_count(const int* __restrict__ dst,
                                               int* __restrict__ cnt, int E) {
  int e = blockIdx.x * 256 + threadIdx.x;
  if (e < E) atomicAdd(&cnt[dst[e]], 1);
}

__global__ __launch_bounds__(256) void k_dinv(const int* __restrict__ cnt,
                                              float* __restrict__ dinv, int N) {
  int i = blockIdx.x * 256 + threadIdx.x;
  if (i < N) dinv[i] = rsqrtf((float)cnt[i] + 1.0f);
}

__global__ __launch_bounds__(256) void k_blocksum(const int* __restrict__ cnt,
                                                  int* __restrict__ bsum, int N) {
  __shared__ int s[256];
  int i = blockIdx.x * 256 + threadIdx.x;
  s[threadIdx.x] = (i < N) ? cnt[i] : 0;
  __syncthreads();
  for (int off = 128; off > 0; off >>= 1) {
    if (threadIdx.x < off) s[threadIdx.x] += s[threadIdx.x + off];
    __syncthreads();
  }
  if (threadIdx.x == 0) bsum[blockIdx.x] = s[0];
}

__global__ __launch_bounds__(512) void k_scan_bsum(int* __restrict__ bsum, int NB,
                                                   int* __restrict__ row_ptr,
                                                   int N, int E) {
  __shared__ int s[512];
  int t = threadIdx.x;
  int v = (t < NB) ? bsum[t] : 0;
  s[t] = v;
  __syncthreads();
  for (int off = 1; off < 512; off <<= 1) {
    int x = (t >= off) ? s[t - off] : 0;
    __syncthreads();
    s[t] += x;
    __syncthreads();
  }
  if (t < NB) bsum[t] = s[t] - v;  // exclusive
  if (t == 0) row_ptr[N] = E;
}

__global__ __launch_bounds__(256) void k_scatter_scan(const int* __restrict__ cnt,
                                                      const int* __restrict__ bsum,
                                                      int* __restrict__ row_ptr, int N) {
  __shared__ int s[256];
  int t = threadIdx.x;
  int i = blockIdx.x * 256 + t;
  int v = (i < N) ? cnt[i] : 0;
  s[t] = v;
  __syncthreads();
  for (int off = 1; off < 256; off <<= 1) {
    int x = (t >= off) ? s[t - off] : 0;
    __syncthreads();
    s[t] += x;
    __syncthreads();
  }
  if (i < N) row_ptr[i] = bsum[blockIdx.x] + s[t] - v;
}

__global__ __launch_bounds__(256) void k_fill(const int* __restrict__ src,
                                              const int* __restrict__ dst,
                                              int* __restrict__ cursor,
                                              int* __restrict__ csr_src, int E) {
  int e = blockIdx.x * 256 + threadIdx.x;
  if (e < E) {
    int d = dst[e];
    int pos = atomicAdd(&cursor[d], 1);
    csr_src[pos] = src[e];
  }
}

// ---------------------------------------------------------------------------
// hs[M][128] (bf16) = (X[M][128] @ W[128][128]) * dinv[row]. f32 math.
// Block tile 64 rows x 128 cols, per-thread 4 rows x 8 cols.
// ---------------------------------------------------------------------------
#define KC 32
__global__ __launch_bounds__(256) void k_gemm128(const float* __restrict__ X,
                                                 const float* __restrict__ W,
                                                 const float* __restrict__ dinv,
                                                 ushort* __restrict__ hs, int M) {
  __shared__ float xs[KC][68];   // xs[k][row]
  __shared__ float wt[KC][132];  // wt[k][col]

  const int t = threadIdx.x;
  const int row0 = blockIdx.x * 64;
  const int trow = t >> 4;  // 0..15 -> 4 rows each
  const int tcol = t & 15;  // 0..15 -> 8 cols each

  float acc[4][8];
#pragma unroll
  for (int i = 0; i < 4; i++)
#pragma unroll
    for (int j = 0; j < 8; j++) acc[i][j] = 0.f;

  for (int k0 = 0; k0 < 128; k0 += KC) {
    {
      int r = t >> 2;
      int kk = (t & 3) * 8;
      int grow = row0 + r;
      float4 v0, v1;
      if (grow < M) {
        const float* p = X + (size_t)grow * 128 + k0 + kk;
        v0 = *(const float4*)p;
        v1 = *(const float4*)(p + 4);
      } else {
        v0 = make_float4(0.f, 0.f, 0.f, 0.f);
        v1 = v0;
      }
      xs[kk + 0][r] = v0.x; xs[kk + 1][r] = v0.y;
      xs[kk + 2][r] = v0.z; xs[kk + 3][r] = v0.w;
      xs[kk + 4][r] = v1.x; xs[kk + 5][r] = v1.y;
      xs[kk + 6][r] = v1.z; xs[kk + 7][r] = v1.w;
    }
    {
#pragma unroll
      for (int q = 0; q < 4; q++) {
        int f4 = t + q * 256;
        int k = f4 >> 5;
        int c4 = f4 & 31;
        float4 v = *(const float4*)(W + (size_t)(k0 + k) * 128 + c4 * 4);
        *(float4*)&wt[k][c4 * 4] = v;
      }
    }
    __syncthreads();

#pragma unroll
    for (int k = 0; k < KC; k++) {
      float4 a = *(const float4*)&xs[k][trow * 4];
      float4 w0 = *(const float4*)&wt[k][tcol * 8];
      float4 w1 = *(const float4*)&wt[k][tcol * 8 + 4];
      float av[4] = {a.x, a.y, a.z, a.w};
      float wv[8] = {w0.x, w0.y, w0.z, w0.w, w1.x, w1.y, w1.z, w1.w};
#pragma unroll
      for (int i = 0; i < 4; i++)
#pragma unroll
        for (int j = 0; j < 8; j++) acc[i][j] = fmaf(av[i], wv[j], acc[i][j]);
    }
    __syncthreads();
  }

#pragma unroll
  for (int i = 0; i < 4; i++) {
    int r = row0 + trow * 4 + i;
    if (r < M) {
      float sc = dinv[r];
      ushort u[8];
#pragma unroll
      for (int j = 0; j < 8; j++) u[j] = f2bf(acc[i][j] * sc);
      *(uint4*)(hs + (size_t)r * 128 + tcol * 8) = *(uint4*)u;  // 16B store
    }
  }
}

// ---------------------------------------------------------------------------
// agg: one WAVE per node (lane owns 2 channels, ushort2 = 4B per lane),
// 4 nodes per 256-thread block. No atomics, no per-edge dinv load.
// out[n] = relu( dinv[n] * (sum_e hs[src_e] + hs[n]) + b )
// ---------------------------------------------------------------------------
__global__ __launch_bounds__(256) void k_agg(const int* __restrict__ row_ptr,
                                             const int* __restrict__ csr_src,
                                             const float* __restrict__ dinv,
                                             const ushort* __restrict__ hs,
                                             const float* __restrict__ bias,
                                             float* __restrict__ out, int N) {
  const int node = blockIdx.x * 4 + (threadIdx.x >> 6);
  if (node >= N) return;
  const int lane = threadIdx.x & 63;
  const ushort2* hp = (const ushort2*)hs;  // 64 ushort2 per row

  const int e0 = row_ptr[node];
  const int e1 = row_ptr[node + 1];

  float ax = 0.f, ay = 0.f;
  int e = e0;
  for (; e + 4 <= e1; e += 4) {
    int s0 = csr_src[e];
    int s1 = csr_src[e + 1];
    int s2 = csr_src[e + 2];
    int s3 = csr_src[e + 3];
    ushort2 v0 = hp[(size_t)s0 * 64 + lane];
    ushort2 v1 = hp[(size_t)s1 * 64 + lane];
    ushort2 v2 = hp[(size_t)s2 * 64 + lane];
    ushort2 v3 = hp[(size_t)s3 * 64 + lane];
    ax += bf2f(v0.x) + bf2f(v1.x) + bf2f(v2.x) + bf2f(v3.x);
    ay += bf2f(v0.y) + bf2f(v1.y) + bf2f(v2.y) + bf2f(v3.y);
  }
  for (; e < e1; ++e) {
    int s = csr_src[e];
    ushort2 v = hp[(size_t)s * 64 + lane];
    ax += bf2f(v.x);
    ay += bf2f(v.y);
  }
  // self contribution
  {
    ushort2 v = hp[(size_t)node * 64 + lane];
    ax += bf2f(v.x);
    ay += bf2f(v.y);
  }
  float dv = dinv[node];
  float2 bv = ((const float2*)bias)[lane];
  float2 o;
  o.x = fmaxf(fmaf(ax, dv, bv.x), 0.f);
  o.y = fmaxf(fmaf(ay, dv, bv.y), 0.f);
  ((float2*)out)[(size_t)node * 64 + lane] = o;
}

// ---------------------------------------------------------------------------

extern "C" void kernel_launch(void* const* d_in, const int* in_sizes, int n_in,
                              void* d_out, int out_size, void* d_ws, size_t ws_size,
                              hipStream_t stream) {
  const float* x  = (const float*)d_in[0];
  const int*   ei = (const int*)d_in[1];
  const float* W1 = (const float*)d_in[2];
  const float* b1 = (const float*)d_in[3];
  const float* W2 = (const float*)d_in[4];
  const float* b2 = (const float*)d_in[5];
  float* out = (float*)d_out;

  const int N = NN;
  const int E = in_sizes[1] / 2;
  const int* src = ei;
  const int* dst = ei + E;

  char* w = (char*)d_ws;
  auto alloc = [&](size_t bytes) {
    char* p = w;
    w += (bytes + 255) & ~(size_t)255;
    return p;
  };
  float*  dinv    = (float*)alloc((size_t)N * 4);
  int*    cnt     = (int*)alloc((size_t)N * 4);
  int*    row_ptr = (int*)alloc((size_t)(N + 1) * 4);
  int*    cursor  = (int*)alloc((size_t)N * 4);
  int*    bsum    = (int*)alloc(512 * 4);
  int*    csr_src = (int*)alloc((size_t)E * 4);
  ushort* hs      = (ushort*)alloc((size_t)N * 128 * 2);  // bf16 scaled rows

  const int NB = (N + 255) / 256;  // 391

  hipMemsetAsync(cnt, 0, (size_t)N * 4, stream);
  k_count<<<(E + 255) / 256, 256, 0, stream>>>(dst, cnt, E);
  k_dinv<<<NB, 256, 0, stream>>>(cnt, dinv, N);
  k_blocksum<<<NB, 256, 0, stream>>>(cnt, bsum, N);
  k_scan_bsum<<<1, 512, 0, stream>>>(bsum, NB, row_ptr, N, E);
  k_scatter_scan<<<NB, 256, 0, stream>>>(cnt, bsum, row_ptr, N);
  hipMemcpyAsync(cursor, row_ptr, (size_t)N * 4, hipMemcpyDeviceToDevice, stream);
  k_fill<<<(E + 255) / 256, 256, 0, stream>>>(src, dst, cursor, csr_src, E);

  const int NAGG = (N + 3) / 4;  // 25000 blocks of 4 waves

  // layer 1
  k_gemm128<<<(N + 63) / 64, 256, 0, stream>>>(x, W1, dinv, hs, N);
  k_agg<<<NAGG, 256, 0, stream>>>(row_ptr, csr_src, dinv, hs, b1, out, N);  // out1 -> d_out
  // layer 2
  k_gemm128<<<(N + 63) / 64, 256, 0, stream>>>(out, W2, dinv, hs, N);
  k_agg<<<NAGG, 256, 0, stream>>>(row_ptr, csr_src, dinv, hs, b2, out, N);
}

// Round 4
// 383.719 us; speedup vs baseline: 1.7128x; 1.4018x over previous
//
#include <hip/hip_runtime.h>

// ---------------------------------------------------------------------------
// GCN 2-layer forward, MI355X.
//   CSR build via bucketed counting sort (coalesced writes, no per-edge
//   random scatter):
//     kb_hist    : 512-bucket histogram (LDS-aggregated atomics)
//     kb_scan    : bucket bases + cursors (1 block)
//     kb_scatter : (src,dst) pairs into bucket runs (128B-avg coalesced runs)
//     kb_sort    : per-bucket exact counting sort in LDS -> csr_src, row_ptr
//   Then per layer:
//     k_gemm128  : f32 vector GEMM, epilogue hs = bf16(h * dinv[row])
//     k_agg      : per-node wave gather of bf16 rows (256B), no atomics
// ---------------------------------------------------------------------------

#define NN 100000
#define NBKT 512
#define BKT_W 196       // nodes per bucket: 512*196 = 100352 >= 100000
#define CHUNK 8192      // edges per block in hist/scatter
#define CAP 6144        // max edges per bucket staged in LDS (avg ~3125)

__device__ __forceinline__ ushort f2bf(float f) {
  unsigned u = __float_as_uint(f);
  unsigned r = (u + 0x7fffu + ((u >> 16) & 1u)) >> 16;  // RNE
  return (ushort)r;
}
__device__ __forceinline__ float bf2f(ushort s) {
  return __uint_as_float(((unsigned)s) << 16);
}

// --- CSR build ---------------------------------------------------------------

__global__ __launch_bounds__(512) void kb_hist(const int* __restrict__ dst,
                                               int* __restrict__ bcnt, int E) {
  __shared__ int h[NBKT];
  for (int i = threadIdx.x; i < NBKT; i += 512) h[i] = 0;
  __syncthreads();
  int base = blockIdx.x * CHUNK;
#pragma unroll 4
  for (int q = 0; q < CHUNK / 512; q++) {
    int e = base + threadIdx.x + q * 512;
    if (e < E) atomicAdd(&h[dst[e] / BKT_W], 1);
  }
  __syncthreads();
  for (int i = threadIdx.x; i < NBKT; i += 512)
    if (h[i]) atomicAdd(&bcnt[i], h[i]);
}

// one block, 512 threads: exclusive scan of 512 bucket counts
__global__ __launch_bounds__(512) void kb_scan(const int* __restrict__ bcnt,
                                               int* __restrict__ bbase,
                                               int* __restrict__ bcur,
                                               int* __restrict__ row_ptr,
                                               int N, int E) {
  __shared__ int s[NBKT];
  int t = threadIdx.x;
  int v = bcnt[t];
  s[t] = v;
  __syncthreads();
  for (int off = 1; off < NBKT; off <<= 1) {
    int x = (t >= off) ? s[t - off] : 0;
    __syncthreads();
    s[t] += x;
    __syncthreads();
  }
  int ex = s[t] - v;
  bbase[t] = ex;
  bcur[t] = ex;
  if (t == NBKT - 1) bbase[NBKT] = E;
  if (t == 0) row_ptr[N] = E;
}

__global__ __launch_bounds__(512) void kb_scatter(const int* __restrict__ src,
                                                  const int* __restrict__ dst,
                                                  int* __restrict__ bcur,
                                                  int2* __restrict__ pairs, int E) {
  __shared__ int h[NBKT];
  __shared__ int gb[NBKT];
  for (int i = threadIdx.x; i < NBKT; i += 512) h[i] = 0;
  __syncthreads();

  const int base = blockIdx.x * CHUNK;
  const int t = threadIdx.x;
  int rank[CHUNK / 512], bkt[CHUNK / 512], sv[CHUNK / 512], dv[CHUNK / 512];
#pragma unroll
  for (int q = 0; q < CHUNK / 512; q++) {
    int e = base + t + q * 512;  // coalesced
    if (e < E) {
      int d = dst[e];
      int b = d / BKT_W;
      bkt[q] = b;
      sv[q] = src[e];
      dv[q] = d;
      rank[q] = atomicAdd(&h[b], 1);
    } else {
      bkt[q] = -1;
    }
  }
  __syncthreads();
  for (int i = t; i < NBKT; i += 512) {
    int c = h[i];
    gb[i] = c ? atomicAdd(&bcur[i], c) : 0;
  }
  __syncthreads();
#pragma unroll
  for (int q = 0; q < CHUNK / 512; q++) {
    if (bkt[q] >= 0) pairs[(size_t)gb[bkt[q]] + rank[q]] = make_int2(sv[q], dv[q]);
  }
}

// one block per bucket: exact counting sort over its <=196 nodes, in LDS
__global__ __launch_bounds__(512) void kb_sort(const int* __restrict__ bbase,
                                               const int2* __restrict__ pairs,
                                               int* __restrict__ csr_src,
                                               int* __restrict__ row_ptr,
                                               int N, int E) {
  __shared__ int cnt[256];    // per-node counts (BKT_W <= 256)
  __shared__ int sc[256];     // scan buffer
  __shared__ int cur[256];    // cursors
  __shared__ int stage[CAP];  // sorted srcs

  const int b = blockIdx.x;
  const int t = threadIdx.x;
  const int lo = bbase[b], hi = bbase[b + 1];
  const int n0 = b * BKT_W;
  int m = hi - lo;
  if (m > CAP) m = CAP;  // statistically impossible; guards LDS

  if (t < 256) cnt[t] = 0;
  __syncthreads();

  for (int i = t; i < m; i += 512) {
    int2 p = pairs[(size_t)lo + i];
    atomicAdd(&cnt[p.y - n0], 1);
  }
  __syncthreads();

  int v = 0;
  if (t < 256) {
    v = cnt[t];
    sc[t] = v;
  }
  __syncthreads();
  for (int off = 1; off < 256; off <<= 1) {
    int x = 0;
    if (t < 256 && t >= off) x = sc[t - off];
    __syncthreads();
    if (t < 256) sc[t] += x;
    __syncthreads();
  }
  if (t < 256) {
    int ex = sc[t] - v;  // exclusive prefix within bucket
    cur[t] = ex;
    int node = n0 + t;
    if (t < BKT_W && node < N) row_ptr[node] = lo + ex;
  }
  __syncthreads();

  for (int i = t; i < m; i += 512) {
    int2 p = pairs[(size_t)lo + i];
    int pos = atomicAdd(&cur[p.y - n0], 1);
    stage[pos] = p.x;
  }
  __syncthreads();

  for (int i = t; i < m; i += 512) csr_src[(size_t)lo + i] = stage[i];
}

__global__ __launch_bounds__(256) void k_dinv(const int* __restrict__ row_ptr,
                                              float* __restrict__ dinv, int N) {
  int i = blockIdx.x * 256 + threadIdx.x;
  if (i < N) dinv[i] = rsqrtf((float)(row_ptr[i + 1] - row_ptr[i]) + 1.0f);
}

// --- GEMM: hs[M][128](bf16) = (X @ W) * dinv[row] ---------------------------
#define KC 32
__global__ __launch_bounds__(256) void k_gemm128(const float* __restrict__ X,
                                                 const float* __restrict__ W,
                                                 const float* __restrict__ dinv,
                                                 ushort* __restrict__ hs, int M) {
  __shared__ float xs[KC][68];
  __shared__ float wt[KC][132];

  const int t = threadIdx.x;
  const int row0 = blockIdx.x * 64;
  const int trow = t >> 4;
  const int tcol = t & 15;

  float acc[4][8];
#pragma unroll
  for (int i = 0; i < 4; i++)
#pragma unroll
    for (int j = 0; j < 8; j++) acc[i][j] = 0.f;

  for (int k0 = 0; k0 < 128; k0 += KC) {
    {
      int r = t >> 2;
      int kk = (t & 3) * 8;
      int grow = row0 + r;
      float4 v0, v1;
      if (grow < M) {
        const float* p = X + (size_t)grow * 128 + k0 + kk;
        v0 = *(const float4*)p;
        v1 = *(const float4*)(p + 4);
      } else {
        v0 = make_float4(0.f, 0.f, 0.f, 0.f);
        v1 = v0;
      }
      xs[kk + 0][r] = v0.x; xs[kk + 1][r] = v0.y;
      xs[kk + 2][r] = v0.z; xs[kk + 3][r] = v0.w;
      xs[kk + 4][r] = v1.x; xs[kk + 5][r] = v1.y;
      xs[kk + 6][r] = v1.z; xs[kk + 7][r] = v1.w;
    }
    {
#pragma unroll
      for (int q = 0; q < 4; q++) {
        int f4 = t + q * 256;
        int k = f4 >> 5;
        int c4 = f4 & 31;
        float4 v = *(const float4*)(W + (size_t)(k0 + k) * 128 + c4 * 4);
        *(float4*)&wt[k][c4 * 4] = v;
      }
    }
    __syncthreads();

#pragma unroll
    for (int k = 0; k < KC; k++) {
      float4 a = *(const float4*)&xs[k][trow * 4];
      float4 w0 = *(const float4*)&wt[k][tcol * 8];
      float4 w1 = *(const float4*)&wt[k][tcol * 8 + 4];
      float av[4] = {a.x, a.y, a.z, a.w};
      float wv[8] = {w0.x, w0.y, w0.z, w0.w, w1.x, w1.y, w1.z, w1.w};
#pragma unroll
      for (int i = 0; i < 4; i++)
#pragma unroll
        for (int j = 0; j < 8; j++) acc[i][j] = fmaf(av[i], wv[j], acc[i][j]);
    }
    __syncthreads();
  }

#pragma unroll
  for (int i = 0; i < 4; i++) {
    int r = row0 + trow * 4 + i;
    if (r < M) {
      float sc = dinv[r];
      ushort u[8];
#pragma unroll
      for (int j = 0; j < 8; j++) u[j] = f2bf(acc[i][j] * sc);
      *(uint4*)(hs + (size_t)r * 128 + tcol * 8) = *(uint4*)u;
    }
  }
}

// --- agg: one wave per node, lane owns 2 channels ---------------------------
__global__ __launch_bounds__(256) void k_agg(const int* __restrict__ row_ptr,
                                             const int* __restrict__ csr_src,
                                             const float* __restrict__ dinv,
                                             const ushort* __restrict__ hs,
                                             const float* __restrict__ bias,
                                             float* __restrict__ out, int N) {
  const int node = blockIdx.x * 4 + (threadIdx.x >> 6);
  if (node >= N) return;
  const int lane = threadIdx.x & 63;
  const ushort2* hp = (const ushort2*)hs;

  const int e0 = row_ptr[node];
  const int e1 = row_ptr[node + 1];

  float ax = 0.f, ay = 0.f;
  int e = e0;
  for (; e + 4 <= e1; e += 4) {
    int s0 = csr_src[e];
    int s1 = csr_src[e + 1];
    int s2 = csr_src[e + 2];
    int s3 = csr_src[e + 3];
    ushort2 v0 = hp[(size_t)s0 * 64 + lane];
    ushort2 v1 = hp[(size_t)s1 * 64 + lane];
    ushort2 v2 = hp[(size_t)s2 * 64 + lane];
    ushort2 v3 = hp[(size_t)s3 * 64 + lane];
    ax += bf2f(v0.x) + bf2f(v1.x) + bf2f(v2.x) + bf2f(v3.x);
    ay += bf2f(v0.y) + bf2f(v1.y) + bf2f(v2.y) + bf2f(v3.y);
  }
  for (; e < e1; ++e) {
    int s = csr_src[e];
    ushort2 v = hp[(size_t)s * 64 + lane];
    ax += bf2f(v.x);
    ay += bf2f(v.y);
  }
  {
    ushort2 v = hp[(size_t)node * 64 + lane];
    ax += bf2f(v.x);
    ay += bf2f(v.y);
  }
  float dv = dinv[node];
  float2 bv = ((const float2*)bias)[lane];
  float2 o;
  o.x = fmaxf(fmaf(ax, dv, bv.x), 0.f);
  o.y = fmaxf(fmaf(ay, dv, bv.y), 0.f);
  ((float2*)out)[(size_t)node * 64 + lane] = o;
}

// ---------------------------------------------------------------------------

extern "C" void kernel_launch(void* const* d_in, const int* in_sizes, int n_in,
                              void* d_out, int out_size, void* d_ws, size_t ws_size,
                              hipStream_t stream) {
  const float* x  = (const float*)d_in[0];
  const int*   ei = (const int*)d_in[1];
  const float* W1 = (const float*)d_in[2];
  const float* b1 = (const float*)d_in[3];
  const float* W2 = (const float*)d_in[4];
  const float* b2 = (const float*)d_in[5];
  float* out = (float*)d_out;

  const int N = NN;
  const int E = in_sizes[1] / 2;
  const int* src = ei;
  const int* dst = ei + E;

  char* w = (char*)d_ws;
  auto alloc = [&](size_t bytes) {
    char* p = w;
    w += (bytes + 255) & ~(size_t)255;
    return p;
  };
  float*  dinv    = (float*)alloc((size_t)N * 4);
  int*    row_ptr = (int*)alloc((size_t)(N + 1) * 4);
  int*    bcnt    = (int*)alloc(NBKT * 4);
  int*    bbase   = (int*)alloc((NBKT + 1) * 4);
  int*    bcur    = (int*)alloc(NBKT * 4);
  int*    csr_src = (int*)alloc((size_t)E * 4);
  int2*   pairs   = (int2*)alloc((size_t)E * 8);
  ushort* hs      = (ushort*)alloc((size_t)N * 128 * 2);

  const int EB = (E + CHUNK - 1) / CHUNK;  // 196 blocks

  hipMemsetAsync(bcnt, 0, NBKT * 4, stream);
  kb_hist<<<EB, 512, 0, stream>>>(dst, bcnt, E);
  kb_scan<<<1, 512, 0, stream>>>(bcnt, bbase, bcur, row_ptr, N, E);
  kb_scatter<<<EB, 512, 0, stream>>>(src, dst, bcur, pairs, E);
  kb_sort<<<NBKT, 512, 0, stream>>>(bbase, pairs, csr_src, row_ptr, N, E);
  k_dinv<<<(N + 255) / 256, 256, 0, stream>>>(row_ptr, dinv, N);

  const int NAGG = (N + 3) / 4;

  // layer 1
  k_gemm128<<<(N + 63) / 64, 256, 0, stream>>>(x, W1, dinv, hs, N);
  k_agg<<<NAGG, 256, 0, stream>>>(row_ptr, csr_src, dinv, hs, b1, out, N);
  // layer 2
  k_gemm128<<<(N + 63) / 64, 256, 0, stream>>>(out, W2, dinv, hs, N);
  k_agg<<<NAGG, 256, 0, stream>>>(row_ptr, csr_src, dinv, hs, b2, out, N);
}

// Round 5
// 345.124 us; speedup vs baseline: 1.9043x; 1.1118x over previous
//
#include <hip/hip_runtime.h>

// ---------------------------------------------------------------------------
// GCN 2-layer forward, MI355X.
//   CSR build via bucketed counting sort (unchanged from r3).
//   Per layer:
//     k_gemm_mfma : hs = bf16((X @ W) * dinv[row]) via split-bf16 MFMA
//                   (x=hi+lo, W=hi+lo; acc += Ah*Bh + Ah*Bl + Al*Bh; err ~2^-17)
//     k_agg       : per-node wave gather of bf16 rows (256B), no atomics
// ---------------------------------------------------------------------------

#define NN 100000
#define NBKT 512
#define BKT_W 196
#define CHUNK 8192
#define CAP 6144

typedef __attribute__((ext_vector_type(8))) short bf16x8;
typedef __attribute__((ext_vector_type(4))) float f32x4;

__device__ __forceinline__ ushort f2bf(float f) {
  unsigned u = __float_as_uint(f);
  unsigned r = (u + 0x7fffu + ((u >> 16) & 1u)) >> 16;  // RNE
  return (ushort)r;
}
__device__ __forceinline__ float bf2f(ushort s) {
  return __uint_as_float(((unsigned)s) << 16);
}
// pack hi16(u_even) -> low half, hi16(u_odd) -> high half (one v_perm after folding)
__device__ __forceinline__ unsigned hipair(unsigned ue, unsigned uo) {
  return (uo & 0xffff0000u) | (ue >> 16);
}

// --- CSR build (unchanged) --------------------------------------------------

__global__ __launch_bounds__(512) void kb_hist(const int* __restrict__ dst,
                                               int* __restrict__ bcnt, int E) {
  __shared__ int h[NBKT];
  for (int i = threadIdx.x; i < NBKT; i += 512) h[i] = 0;
  __syncthreads();
  int base = blockIdx.x * CHUNK;
#pragma unroll 4
  for (int q = 0; q < CHUNK / 512; q++) {
    int e = base + threadIdx.x + q * 512;
    if (e < E) atomicAdd(&h[dst[e] / BKT_W], 1);
  }
  __syncthreads();
  for (int i = threadIdx.x; i < NBKT; i += 512)
    if (h[i]) atomicAdd(&bcnt[i], h[i]);
}

__global__ __launch_bounds__(512) void kb_scan(const int* __restrict__ bcnt,
                                               int* __restrict__ bbase,
                                               int* __restrict__ bcur,
                                               int* __restrict__ row_ptr,
                                               int N, int E) {
  __shared__ int s[NBKT];
  int t = threadIdx.x;
  int v = bcnt[t];
  s[t] = v;
  __syncthreads();
  for (int off = 1; off < NBKT; off <<= 1) {
    int x = (t >= off) ? s[t - off] : 0;
    __syncthreads();
    s[t] += x;
    __syncthreads();
  }
  int ex = s[t] - v;
  bbase[t] = ex;
  bcur[t] = ex;
  if (t == NBKT - 1) bbase[NBKT] = E;
  if (t == 0) row_ptr[N] = E;
}

__global__ __launch_bounds__(512) void kb_scatter(const int* __restrict__ src,
                                                  const int* __restrict__ dst,
                                                  int* __restrict__ bcur,
                                                  int2* __restrict__ pairs, int E) {
  __shared__ int h[NBKT];
  __shared__ int gb[NBKT];
  for (int i = threadIdx.x; i < NBKT; i += 512) h[i] = 0;
  __syncthreads();

  const int base = blockIdx.x * CHUNK;
  const int t = threadIdx.x;
  int rank[CHUNK / 512], bkt[CHUNK / 512], sv[CHUNK / 512], dv[CHUNK / 512];
#pragma unroll
  for (int q = 0; q < CHUNK / 512; q++) {
    int e = base + t + q * 512;
    if (e < E) {
      int d = dst[e];
      int b = d / BKT_W;
      bkt[q] = b;
      sv[q] = src[e];
      dv[q] = d;
      rank[q] = atomicAdd(&h[b], 1);
    } else {
      bkt[q] = -1;
    }
  }
  __syncthreads();
  for (int i = t; i < NBKT; i += 512) {
    int c = h[i];
    gb[i] = c ? atomicAdd(&bcur[i], c) : 0;
  }
  __syncthreads();
#pragma unroll
  for (int q = 0; q < CHUNK / 512; q++) {
    if (bkt[q] >= 0) pairs[(size_t)gb[bkt[q]] + rank[q]] = make_int2(sv[q], dv[q]);
  }
}

__global__ __launch_bounds__(512) void kb_sort(const int* __restrict__ bbase,
                                               const int2* __restrict__ pairs,
                                               int* __restrict__ csr_src,
                                               int* __restrict__ row_ptr,
                                               int N, int E) {
  __shared__ int cnt[256];
  __shared__ int sc[256];
  __shared__ int cur[256];
  __shared__ int stage[CAP];

  const int b = blockIdx.x;
  const int t = threadIdx.x;
  const int lo = bbase[b], hi = bbase[b + 1];
  const int n0 = b * BKT_W;
  int m = hi - lo;
  if (m > CAP) m = CAP;

  if (t < 256) cnt[t] = 0;
  __syncthreads();

  for (int i = t; i < m; i += 512) {
    int2 p = pairs[(size_t)lo + i];
    atomicAdd(&cnt[p.y - n0], 1);
  }
  __syncthreads();

  int v = 0;
  if (t < 256) {
    v = cnt[t];
    sc[t] = v;
  }
  __syncthreads();
  for (int off = 1; off < 256; off <<= 1) {
    int x = 0;
    if (t < 256 && t >= off) x = sc[t - off];
    __syncthreads();
    if (t < 256) sc[t] += x;
    __syncthreads();
  }
  if (t < 256) {
    int ex = sc[t] - v;
    cur[t] = ex;
    int node = n0 + t;
    if (t < BKT_W && node < N) row_ptr[node] = lo + ex;
  }
  __syncthreads();

  for (int i = t; i < m; i += 512) {
    int2 p = pairs[(size_t)lo + i];
    int pos = atomicAdd(&cur[p.y - n0], 1);
    stage[pos] = p.x;
  }
  __syncthreads();

  for (int i = t; i < m; i += 512) csr_src[(size_t)lo + i] = stage[i];
}

__global__ __launch_bounds__(256) void k_dinv(const int* __restrict__ row_ptr,
                                              float* __restrict__ dinv, int N) {
  int i = blockIdx.x * 256 + threadIdx.x;
  if (i < N) dinv[i] = rsqrtf((float)(row_ptr[i + 1] - row_ptr[i]) + 1.0f);
}

// --- MFMA GEMM: hs[M][128](bf16) = (X[M][128] @ W[128][128]) * dinv[row] ----
// Split-precision: x = hi + lo (bf16 trunc + exact residual), same for W.
// acc += Ah*Bh + Ah*Bl + Al*Bh  (lo*lo dropped, ~2^-18). f32 MFMA accumulate.
// Block: 128 rows, 4 waves x 32 rows. W staged in LDS transposed [n][k],
// XOR-swizzled ((n&7)<<4 on byte addr) -> conflict-free ds_read_b128.

__device__ __forceinline__ void cvt_row(const float* __restrict__ p,
                                        bf16x8* hi, bf16x8* lo) {
  float4 v0 = *(const float4*)p;
  float4 v1 = *(const float4*)(p + 4);
  float f[8] = {v0.x, v0.y, v0.z, v0.w, v1.x, v1.y, v1.z, v1.w};
  unsigned hw[4], lw[4];
#pragma unroll
  for (int i = 0; i < 4; ++i) {
    unsigned u0 = __float_as_uint(f[2 * i]);
    unsigned u1 = __float_as_uint(f[2 * i + 1]);
    float l0 = f[2 * i] - __uint_as_float(u0 & 0xffff0000u);      // exact (Sterbenz)
    float l1 = f[2 * i + 1] - __uint_as_float(u1 & 0xffff0000u);  // exact
    hw[i] = hipair(u0, u1);
    lw[i] = hipair(__float_as_uint(l0), __float_as_uint(l1));
  }
  uint4 H = make_uint4(hw[0], hw[1], hw[2], hw[3]);
  uint4 L = make_uint4(lw[0], lw[1], lw[2], lw[3]);
  *hi = __builtin_bit_cast(bf16x8, H);
  *lo = __builtin_bit_cast(bf16x8, L);
}

__global__ __launch_bounds__(256) void k_gemm_mfma(const float* __restrict__ X,
                                                   const float* __restrict__ W,
                                                   const float* __restrict__ dinv,
                                                   ushort* __restrict__ hs, int M) {
  __shared__ ushort wt_hi[128 * 128];  // [n][k] bf16-hi, XOR-swizzled, 32KB
  __shared__ ushort wt_lo[128 * 128];  // [n][k] bf16-lo, 32KB

  const int t = threadIdx.x;

  // ---- stage W: read f32 [k][n] coalesced, split, write transposed [n][k]
  {
    const int n4 = (t & 31) * 4;       // columns n4..n4+3
    const int kq0 = (t >> 5) * 4;      // k-quad
    for (int it = 0; it < 4; ++it) {
      const int kq = kq0 + it * 32;
      float4 r[4];
#pragma unroll
      for (int j = 0; j < 4; ++j)
        r[j] = *(const float4*)(W + (size_t)(kq + j) * 128 + n4);
#pragma unroll
      for (int q = 0; q < 4; ++q) {
        const int n = n4 + q;
        unsigned u[4], l[4];
#pragma unroll
        for (int j = 0; j < 4; ++j) {
          float f = ((const float*)&r[j])[q];
          u[j] = __float_as_uint(f);
          float lf = f - __uint_as_float(u[j] & 0xffff0000u);
          l[j] = __float_as_uint(lf);
        }
        uint2 hw = make_uint2(hipair(u[0], u[1]), hipair(u[2], u[3]));
        uint2 lw = make_uint2(hipair(l[0], l[1]), hipair(l[2], l[3]));
        const int bo = (n * 256 + kq * 2) ^ ((n & 7) << 4);
        *(uint2*)((char*)wt_hi + bo) = hw;
        *(uint2*)((char*)wt_lo + bo) = lw;
      }
    }
  }
  __syncthreads();

  const int wv = t >> 6;
  const int lane = t & 63;
  const int r0 = blockIdx.x * 128 + wv * 32;
  const int la = lane & 15;
  const int kg = (lane >> 4) * 8;
  const int rowA = min(r0 + la, M - 1);
  const int rowB = min(r0 + 16 + la, M - 1);

  f32x4 acc[2][8];
#pragma unroll
  for (int rs = 0; rs < 2; ++rs)
#pragma unroll
    for (int ct = 0; ct < 8; ++ct) acc[rs][ct] = (f32x4)(0.f);

#pragma unroll
  for (int ks = 0; ks < 4; ++ks) {
    const int koff = ks * 32 + kg;
    bf16x8 ah0, al0, ah1, al1;
    cvt_row(X + (size_t)rowA * 128 + koff, &ah0, &al0);
    cvt_row(X + (size_t)rowB * 128 + koff, &ah1, &al1);
#pragma unroll
    for (int ct = 0; ct < 8; ++ct) {
      const int n = ct * 16 + la;
      const int bo = (n * 256 + koff * 2) ^ ((n & 7) << 4);
      bf16x8 bh = *(const bf16x8*)((const char*)wt_hi + bo);
      bf16x8 bl = *(const bf16x8*)((const char*)wt_lo + bo);
      acc[0][ct] = __builtin_amdgcn_mfma_f32_16x16x32_bf16(ah0, bh, acc[0][ct], 0, 0, 0);
      acc[0][ct] = __builtin_amdgcn_mfma_f32_16x16x32_bf16(ah0, bl, acc[0][ct], 0, 0, 0);
      acc[0][ct] = __builtin_amdgcn_mfma_f32_16x16x32_bf16(al0, bh, acc[0][ct], 0, 0, 0);
      acc[1][ct] = __builtin_amdgcn_mfma_f32_16x16x32_bf16(ah1, bh, acc[1][ct], 0, 0, 0);
      acc[1][ct] = __builtin_amdgcn_mfma_f32_16x16x32_bf16(ah1, bl, acc[1][ct], 0, 0, 0);
      acc[1][ct] = __builtin_amdgcn_mfma_f32_16x16x32_bf16(al1, bh, acc[1][ct], 0, 0, 0);
    }
  }

  // epilogue: C/D layout col = lane&15, row = (lane>>4)*4 + j
#pragma unroll
  for (int rs = 0; rs < 2; ++rs) {
#pragma unroll
    for (int j = 0; j < 4; ++j) {
      int r = r0 + rs * 16 + (lane >> 4) * 4 + j;
      if (r < M) {
        float sc = dinv[r];
#pragma unroll
        for (int ct = 0; ct < 8; ++ct)
          hs[(size_t)r * 128 + ct * 16 + la] = f2bf(acc[rs][ct][j] * sc);
      }
    }
  }
}

// --- agg: one wave per node, lane owns 2 channels, unroll 8 -----------------
__global__ __launch_bounds__(256) void k_agg(const int* __restrict__ row_ptr,
                                             const int* __restrict__ csr_src,
                                             const float* __restrict__ dinv,
                                             const ushort* __restrict__ hs,
                                             const float* __restrict__ bias,
                                             float* __restrict__ out, int N) {
  const int node = blockIdx.x * 4 + (threadIdx.x >> 6);
  if (node >= N) return;
  const int lane = threadIdx.x & 63;
  const ushort2* hp = (const ushort2*)hs;

  const int e0 = row_ptr[node];
  const int e1 = row_ptr[node + 1];

  float ax = 0.f, ay = 0.f;
  int e = e0;
  for (; e + 8 <= e1; e += 8) {
    int s[8];
#pragma unroll
    for (int q = 0; q < 8; q++) s[q] = csr_src[e + q];
    ushort2 v[8];
#pragma unroll
    for (int q = 0; q < 8; q++) v[q] = hp[(size_t)s[q] * 64 + lane];
#pragma unroll
    for (int q = 0; q < 8; q++) {
      ax += bf2f(v[q].x);
      ay += bf2f(v[q].y);
    }
  }
  for (; e < e1; ++e) {
    int s = csr_src[e];
    ushort2 v = hp[(size_t)s * 64 + lane];
    ax += bf2f(v.x);
    ay += bf2f(v.y);
  }
  {
    ushort2 v = hp[(size_t)node * 64 + lane];
    ax += bf2f(v.x);
    ay += bf2f(v.y);
  }
  float dv = dinv[node];
  float2 bv = ((const float2*)bias)[lane];
  float2 o;
  o.x = fmaxf(fmaf(ax, dv, bv.x), 0.f);
  o.y = fmaxf(fmaf(ay, dv, bv.y), 0.f);
  ((float2*)out)[(size_t)node * 64 + lane] = o;
}

// ---------------------------------------------------------------------------

extern "C" void kernel_launch(void* const* d_in, const int* in_sizes, int n_in,
                              void* d_out, int out_size, void* d_ws, size_t ws_size,
                              hipStream_t stream) {
  const float* x  = (const float*)d_in[0];
  const int*   ei = (const int*)d_in[1];
  const float* W1 = (const float*)d_in[2];
  const float* b1 = (const float*)d_in[3];
  const float* W2 = (const float*)d_in[4];
  const float* b2 = (const float*)d_in[5];
  float* out = (float*)d_out;

  const int N = NN;
  const int E = in_sizes[1] / 2;
  const int* src = ei;
  const int* dst = ei + E;

  char* w = (char*)d_ws;
  auto alloc = [&](size_t bytes) {
    char* p = w;
    w += (bytes + 255) & ~(size_t)255;
    return p;
  };
  float*  dinv    = (float*)alloc((size_t)N * 4);
  int*    row_ptr = (int*)alloc((size_t)(N + 1) * 4);
  int*    bcnt    = (int*)alloc(NBKT * 4);
  int*    bbase   = (int*)alloc((NBKT + 1) * 4);
  int*    bcur    = (int*)alloc(NBKT * 4);
  int*    csr_src = (int*)alloc((size_t)E * 4);
  int2*   pairs   = (int2*)alloc((size_t)E * 8);
  ushort* hs      = (ushort*)alloc((size_t)N * 128 * 2);

  const int EB = (E + CHUNK - 1) / CHUNK;

  hipMemsetAsync(bcnt, 0, NBKT * 4, stream);
  kb_hist<<<EB, 512, 0, stream>>>(dst, bcnt, E);
  kb_scan<<<1, 512, 0, stream>>>(bcnt, bbase, bcur, row_ptr, N, E);
  kb_scatter<<<EB, 512, 0, stream>>>(src, dst, bcur, pairs, E);
  kb_sort<<<NBKT, 512, 0, stream>>>(bbase, pairs, csr_src, row_ptr, N, E);
  k_dinv<<<(N + 255) / 256, 256, 0, stream>>>(row_ptr, dinv, N);

  const int NAGG = (N + 3) / 4;
  const int GB = (N + 127) / 128;

  // layer 1
  k_gemm_mfma<<<GB, 256, 0, stream>>>(x, W1, dinv, hs, N);
  k_agg<<<NAGG, 256, 0, stream>>>(row_ptr, csr_src, dinv, hs, b1, out, N);
  // layer 2
  k_gemm_mfma<<<GB, 256, 0, stream>>>(out, W2, dinv, hs, N);
  k_agg<<<NAGG, 256, 0, stream>>>(row_ptr, csr_src, dinv, hs, b2, out, N);
}